// Round 2
// baseline (1311.998 us; speedup 1.0000x reference)
//
#include <hip/hip_runtime.h>

// Problem constants (T,B,N,D) = (32,16,2048,64)
constexpr int T = 32;
constexpr int NROWS = 16 * 2048;   // B*N = 32768
constexpr int D = 64;
constexpr long DYN = (long)T * NROWS * D;   // all_dyn elements
constexpr long FIN = (long)NROWS * D;       // final elements

typedef float vf4 __attribute__((ext_vector_type(4)));   // native vector: OK for nontemporal builtins

// Block: 256 threads = 4 waves. Wave q handles output columns [16q,16q+16)
// for the block's 64 rows (lane r = row within block tile).
// LDS x-buffer: x[k][col], k = concat(h:0..63, s:64..127), col = r ^ ((k>>1)&31)
// (swizzle keeps transpose-writes AND per-lane reads bank-conflict-free).

__global__ __launch_bounds__(256, 2) void evo_kernel(
    const float* __restrict__ stat,   // [T][NROWS][D]
    const float* __restrict__ thre,   // [T][NROWS]
    const float* __restrict__ h0,     // [NROWS][D]
    const float* __restrict__ w1,     // [128][64]
    float* __restrict__ out)          // all_dyn | final | diffs
{
    __shared__ float xs[2][128][64];  // 64 KB double buffer

    const int tid = threadIdx.x;
    const int r   = tid & 63;
    const int q   = __builtin_amdgcn_readfirstlane(tid >> 6);  // wave id, scalar
    const int row0 = blockIdx.x * 64;
    const int row  = row0 + r;

    const float* __restrict__ wq = w1 + q * 16;   // scalar pointer

    float h[16];

    // ---- prologue: load h0, emit all_dyn[0] = h0 copy ----
    {
        const vf4* hp = reinterpret_cast<const vf4*>(h0 + (long)row * D + q * 16);
        vf4* op = reinterpret_cast<vf4*>(out + (long)row * D + q * 16);
#pragma unroll
        for (int i = 0; i < 4; ++i) {
            vf4 v = hp[i];
            h[4*i+0] = v.x; h[4*i+1] = v.y; h[4*i+2] = v.z; h[4*i+3] = v.w;
            __builtin_nontemporal_store(v, op + i);
        }
    }

    // ---- prefetch s tile for tt=1 (coalesced: tile is 16 KB contiguous) ----
    vf4 sr[4];
    {
        const vf4* sp = reinterpret_cast<const vf4*>(stat + ((long)1 * NROWS + row0) * D);
#pragma unroll
        for (int i = 0; i < 4; ++i) sr[i] = __builtin_nontemporal_load(sp + tid + 256 * i);
    }

    int p = 0;
#pragma unroll 1
    for (int tt = 1; tt < T; ++tt) {
        // ---- stage h into xs[p] (k = 16q+jj), conflict-free ----
#pragma unroll
        for (int jj = 0; jj < 16; ++jj) {
            int k = q * 16 + jj;
            xs[p][k][r ^ ((k >> 1) & 31)] = h[jj];
        }
        // ---- stage s tile into xs[p] (transpose write, swizzled) ----
#pragma unroll
        for (int i = 0; i < 4; ++i) {
            int f  = (tid + 256 * i) * 4;   // flat float index in 64x64 tile
            int rr = f >> 6;                // row within tile
            int dd = f & 63;                // feature
            int k  = 64 + dd;
            xs[p][k    ][rr ^ (((k    ) >> 1) & 31)] = sr[i].x;
            xs[p][k + 1][rr ^ (((k + 1) >> 1) & 31)] = sr[i].y;
            xs[p][k + 2][rr ^ (((k + 2) >> 1) & 31)] = sr[i].z;
            xs[p][k + 3][rr ^ (((k + 3) >> 1) & 31)] = sr[i].w;
        }
        __syncthreads();   // single barrier per step (double buffer)

        // ---- prefetch next step's s tile (hidden under FMA phase) ----
        if (tt + 1 < T) {
            const vf4* sp = reinterpret_cast<const vf4*>(stat + ((long)(tt + 1) * NROWS + row0) * D);
#pragma unroll
            for (int i = 0; i < 4; ++i) sr[i] = __builtin_nontemporal_load(sp + tid + 256 * i);
        }

        float tg = thre[(long)tt * NROWS + row];

        // ---- z = [h,s] @ w1 column block; weights via scalar loads ----
        float z[16];
#pragma unroll
        for (int jj = 0; jj < 16; ++jj) z[jj] = 0.0f;

#pragma unroll 2
        for (int k = 0; k < 128; k += 2) {
            int col  = r ^ ((k >> 1) & 31);     // same swizzle for k and k+1
            float x0 = xs[p][k][col];
            float x1 = xs[p][k + 1][col];
            const float* wk = wq + k * 64;      // uniform address -> s_load
#pragma unroll
            for (int jj = 0; jj < 16; ++jj) {
                z[jj] = fmaf(x0, wk[jj],      z[jj]);
                z[jj] = fmaf(x1, wk[64 + jj], z[jj]);
            }
        }

        // ---- gate + sigmoid; z becomes diff ----
#pragma unroll
        for (int jj = 0; jj < 16; ++jj) {
            float v  = fmaf(tg, z[jj] - h[jj], h[jj]);   // z*t + h*(1-t)
            float hn = 1.0f / (1.0f + __expf(-v));
            z[jj] = hn - h[jj];
            h[jj] = hn;
        }

        // ---- stores: all_dyn[tt], diffs[tt-1], final (tt==T-1) ----
        {
            vf4* od = reinterpret_cast<vf4*>(out + ((long)tt * NROWS + row) * D + q * 16);
            vf4* dd = reinterpret_cast<vf4*>(out + DYN + FIN + ((long)(tt - 1) * NROWS + row) * D + q * 16);
#pragma unroll
            for (int i = 0; i < 4; ++i) {
                vf4 hv = { h[4*i], h[4*i+1], h[4*i+2], h[4*i+3] };
                vf4 zv = { z[4*i], z[4*i+1], z[4*i+2], z[4*i+3] };
                __builtin_nontemporal_store(hv, od + i);
                __builtin_nontemporal_store(zv, dd + i);
            }
            if (tt == T - 1) {
                vf4* fp = reinterpret_cast<vf4*>(out + DYN + (long)row * D + q * 16);
#pragma unroll
                for (int i = 0; i < 4; ++i) {
                    vf4 hv = { h[4*i], h[4*i+1], h[4*i+2], h[4*i+3] };
                    __builtin_nontemporal_store(hv, fp + i);
                }
            }
        }

        p ^= 1;
    }
}

extern "C" void kernel_launch(void* const* d_in, const int* in_sizes, int n_in,
                              void* d_out, int out_size, void* d_ws, size_t ws_size,
                              hipStream_t stream) {
    const float* stat = (const float*)d_in[0];   // all_data_static [T,B,N,D]
    const float* thre = (const float*)d_in[1];   // thre_nc [T,B,N,1]
    const float* h0   = (const float*)d_in[2];   // all_data_dynamic_now [B,N,D]
    const float* w1   = (const float*)d_in[3];   // w1 [2D, D]
    float* out = (float*)d_out;

    dim3 grid(NROWS / 64);   // 512 blocks
    dim3 block(256);
    evo_kernel<<<grid, block, 0, stream>>>(stat, thre, h0, w1, out);
}